// Round 1
// baseline (589.354 us; speedup 1.0000x reference)
//
#include <hip/hip_runtime.h>
#include <math.h>

// SparseEdgeEmbeddingV3: out[1, N, N, 16] fp32.
// keep(i,j) = exp(-d2/(2*sig_max^2)) >= 0.9  &&  d2 > 0  &&  i != j
// out[i,j,c] = keep ? exp(-d2 * 1/(2*sigma_c^2)) : 0
//
// Write-BW bound: 604 MB of output per launch (harness re-poisons d_out).
// One thread per (pair, channel-quad): each lane stores one float4 -> a wave
// stores 1024 contiguous bytes (perfect coalescing).

constexpr int N_PTS = 3072;
constexpr int N_OUT = 16;

__global__ __launch_bounds__(256) void sparse_edge_kernel(
    const float* __restrict__ coord,   // [N,3]
    const float* __restrict__ sigma,   // [16]
    float* __restrict__ out,           // [N,N,16]
    long long total4)                  // N*N*4 float4 slots
{
    long long t = (long long)blockIdx.x * 256 + threadIdx.x;
    if (t >= total4) return;

    int p  = (int)(t >> 2);   // pair index i*N + j
    int c4 = (int)(t & 3);    // which quad of channels
    int i  = p / N_PTS;       // compile-time const divisor -> magic mul
    int j  = p - i * N_PTS;

    float xi = coord[3 * i + 0], yi = coord[3 * i + 1], zi = coord[3 * i + 2];
    float xj = coord[3 * j + 0], yj = coord[3 * j + 1], zj = coord[3 * j + 2];

    // Replicate numpy bit-for-bit as closely as possible (keep-flip hazard):
    // sq = (x*x + y*y) + z*z, all round-to-nearest, NO fma contraction.
    float sqi = __fadd_rn(__fadd_rn(__fmul_rn(xi, xi), __fmul_rn(yi, yi)),
                          __fmul_rn(zi, zi));
    float sqj = __fadd_rn(__fadd_rn(__fmul_rn(xj, xj), __fmul_rn(yj, yj)),
                          __fmul_rn(zj, zj));
    // BLAS-sgemm-style dot: fma(z, z, fma(y, y, x*x))
    float dot = __fmul_rn(xi, xj);
    dot = __builtin_fmaf(yi, yj, dot);
    dot = __builtin_fmaf(zi, zj, dot);

    float d2 = __fsub_rn(__fadd_rn(sqi, sqj), __fmul_rn(2.0f, dot));
    d2 = fmaxf(d2, 0.0f);

    float smax = sigma[N_OUT - 1];                              // 3.0
    float den  = __fmul_rn(__fmul_rn(2.0f, smax), smax);        // 18.0 exact

    // keep decision. Boundary d2* = -18*ln(0.9) ~= 1.89651.
    // d2 <= 1.8  -> exp >= 0.90484, margin 4.8e-3 >> any rounding: keep.
    // d2 >  2.0  -> exp <= 0.89484, margin 5.2e-3: drop.
    // Only the 1.8..2.0 band (~0.4% of pairs) needs the exact check; do it
    // with the same fp32 division numpy does, then exp in double so OUR exp
    // rounding contributes nothing to the boundary.
    bool keep = (i != j) && (d2 > 0.0f);
    if (keep) {
        if (d2 > 2.0f) {
            keep = false;
        } else if (d2 > 1.8f) {
            float qf = __fdiv_rn(-d2, den);          // fp32 rn, like numpy
            keep = (exp((double)qf) >= 0.9);
        }
    }

    float4 v = make_float4(0.0f, 0.0f, 0.0f, 0.0f);
    if (keep) {
        // inv_two_sig2 = 1/((2*s)*s), all fp32 rn like numpy
        float s0 = sigma[4 * c4 + 0];
        float s1 = sigma[4 * c4 + 1];
        float s2 = sigma[4 * c4 + 2];
        float s3 = sigma[4 * c4 + 3];
        float i0 = __fdiv_rn(1.0f, __fmul_rn(__fmul_rn(2.0f, s0), s0));
        float i1 = __fdiv_rn(1.0f, __fmul_rn(__fmul_rn(2.0f, s1), s1));
        float i2 = __fdiv_rn(1.0f, __fmul_rn(__fmul_rn(2.0f, s2), s2));
        float i3 = __fdiv_rn(1.0f, __fmul_rn(__fmul_rn(2.0f, s3), s3));
        v.x = expf(__fmul_rn(-d2, i0));
        v.y = expf(__fmul_rn(-d2, i1));
        v.z = expf(__fmul_rn(-d2, i2));
        v.w = expf(__fmul_rn(-d2, i3));
    }

    reinterpret_cast<float4*>(out)[t] = v;
}

extern "C" void kernel_launch(void* const* d_in, const int* in_sizes, int n_in,
                              void* d_out, int out_size, void* d_ws, size_t ws_size,
                              hipStream_t stream) {
    const float* coord = (const float*)d_in[0];   // [3072, 3] fp32
    const float* sigma = (const float*)d_in[1];   // [16] fp32
    float* out = (float*)d_out;                   // [1, 3072, 3072, 16] fp32

    const long long total4 = (long long)N_PTS * N_PTS * 4;  // 37,748,736
    const int block = 256;
    const long long grid = (total4 + block - 1) / block;    // 147,456

    hipLaunchKernelGGL(sparse_edge_kernel, dim3((unsigned)grid), dim3(block),
                       0, stream, coord, sigma, out, total4);
}

// Round 3
// 565.473 us; speedup vs baseline: 1.0422x; 1.0422x over previous
//
#include <hip/hip_runtime.h>
#include <math.h>

// SparseEdgeEmbeddingV3: out[1, N, N, 16] fp32, N=3072.
// keep(i,j) = exp(-d2/18) >= 0.9 && d2 > 0 && i != j   (sig_max = 3.0)
// out[i,j,c] = keep ? exp(-d2 / (2*sigma_c^2)) : 0
//
// Write-BW bound: 604 MB of output per launch. One thread per (pair,
// channel-quad): lane stores one contiguous float4 -> wave stores 1 KB
// contiguous (perfect coalescing). 2D grid: blockIdx.y = row i,
// blockIdx.x = 64-wide j-chunk -> no integer division anywhere.
//
// KEEP decision numerics are bit-identical to the R1-passing kernel
// (matches numpy's boundary behavior on this fixed input — do not touch):
//   sq = (x*x + y*y) + z*z  (rn, no fma)
//   dot = fma(z,z, fma(y,y, x*x))
//   d2 = max((sqi+sqj) - 2*dot, 0)
//   d2<=1.8 keep, d2>2.0 drop, band decided by f64 exp(fp32(-d2/18)) >= 0.9
// Kept VALUES only need |err| << 0.02 -> native rcp + __expf (err ~2e-6).

constexpr int N_PTS = 3072;

// Native clang vector type — __builtin_nontemporal_store requires this
// (HIP's float4 is a class and is rejected).
typedef float v4f __attribute__((ext_vector_type(4)));

__global__ __launch_bounds__(256) void sparse_edge_kernel(
    const float* __restrict__ coord,   // [N,3]
    const float* __restrict__ sigma,   // [16]
    float* __restrict__ out)           // [N,N,16]
{
    const int i  = blockIdx.y;
    const int j  = (blockIdx.x << 6) + (threadIdx.x >> 2);  // 64 j per block
    const int c4 = threadIdx.x & 3;

    const float xi = coord[3 * i + 0], yi = coord[3 * i + 1], zi = coord[3 * i + 2];
    const float xj = coord[3 * j + 0], yj = coord[3 * j + 1], zj = coord[3 * j + 2];

    // --- keep decision: EXACT R1 numerics ---
    float sqi = __fadd_rn(__fadd_rn(__fmul_rn(xi, xi), __fmul_rn(yi, yi)),
                          __fmul_rn(zi, zi));
    float sqj = __fadd_rn(__fadd_rn(__fmul_rn(xj, xj), __fmul_rn(yj, yj)),
                          __fmul_rn(zj, zj));
    float dot = __fmul_rn(xi, xj);
    dot = __builtin_fmaf(yi, yj, dot);
    dot = __builtin_fmaf(zi, zj, dot);

    float d2 = __fsub_rn(__fadd_rn(sqi, sqj), __fmul_rn(2.0f, dot));
    d2 = fmaxf(d2, 0.0f);

    bool keep = (i != j) && (d2 > 0.0f) && !(d2 > 2.0f);
    if (keep && d2 > 1.8f) {
        // Rare band (~0.4% of pairs): decide with numpy-matching arithmetic.
        float smax = sigma[15];                                  // 3.0
        float den  = __fmul_rn(__fmul_rn(2.0f, smax), smax);     // 18.0 exact
        float qf   = __fdiv_rn(-d2, den);                        // fp32 rn
        keep = (exp((double)qf) >= 0.9);
    }

    v4f v = (v4f)(0.0f);
    if (keep) {
        const float4 s = reinterpret_cast<const float4*>(sigma)[c4];
        // inv = 1/(2*s*s) via native rcp; value tolerance is 0.02, err ~1e-7.
        float i0 = __builtin_amdgcn_rcpf(2.0f * s.x * s.x);
        float i1 = __builtin_amdgcn_rcpf(2.0f * s.y * s.y);
        float i2 = __builtin_amdgcn_rcpf(2.0f * s.z * s.z);
        float i3 = __builtin_amdgcn_rcpf(2.0f * s.w * s.w);
        v.x = __expf(-d2 * i0);
        v.y = __expf(-d2 * i1);
        v.z = __expf(-d2 * i2);
        v.w = __expf(-d2 * i3);
    }

    // float4 slot index: (i*N + j)*4 + c4 == base + threadIdx.x (contiguous
    // 4 KB per block). Fits 37.7M slots; size_t for the pointer arithmetic.
    size_t idx = ((size_t)i * N_PTS << 2) + ((size_t)blockIdx.x << 8) + threadIdx.x;
    __builtin_nontemporal_store(v, reinterpret_cast<v4f*>(out) + idx);
}

extern "C" void kernel_launch(void* const* d_in, const int* in_sizes, int n_in,
                              void* d_out, int out_size, void* d_ws, size_t ws_size,
                              hipStream_t stream) {
    const float* coord = (const float*)d_in[0];   // [3072, 3] fp32
    const float* sigma = (const float*)d_in[1];   // [16] fp32
    float* out = (float*)d_out;                   // [1, 3072, 3072, 16] fp32

    dim3 grid(N_PTS / 64, N_PTS);   // (48, 3072)
    dim3 block(256);
    hipLaunchKernelGGL(sparse_edge_kernel, grid, block, 0, stream,
                       coord, sigma, out);
}

// Round 4
// 563.113 us; speedup vs baseline: 1.0466x; 1.0042x over previous
//
#include <hip/hip_runtime.h>
#include <math.h>

// SparseEdgeEmbeddingV3: out[1, N, N, 16] fp32, N=3072.
// keep(i,j) = exp(-d2/18) >= 0.9 && d2 > 0 && i != j   (sig_max = 3.0)
// out[i,j,c] = keep ? exp(-d2 / (2*sigma_c^2)) : 0
//
// Write-BW bound: 604 MB of output per launch (harness re-poisons d_out).
// One thread per (pair, channel-quad): lane stores one contiguous float4 ->
// wave stores 1 KB contiguous. 2D grid: blockIdx.y = i, blockIdx.x = 64-wide
// j-chunk -> no integer division.
//
// R4 A/B vs R3: PLAIN stores instead of __builtin_nontemporal_store.
// Theory: nt bypasses L2 write-combining; the harness fill sustains
// 6.35 TB/s with plain stores. Everything else identical to R3.
//
// KEEP decision numerics bit-identical to the R1/R3-passing kernels
// (matches numpy boundary behavior on this fixed input — do not touch):
//   sq = (x*x + y*y) + z*z  (rn, no fma)
//   dot = fma(z,z, fma(y,y, x*x))
//   d2 = max((sqi+sqj) - 2*dot, 0)
//   d2<=1.8 keep, d2>2.0 drop, band decided by f64 exp(fp32(-d2/18)) >= 0.9
// Kept VALUES only need |err| << 0.02 -> native rcp + __expf.

constexpr int N_PTS = 3072;

__global__ __launch_bounds__(256) void sparse_edge_kernel(
    const float* __restrict__ coord,   // [N,3]
    const float* __restrict__ sigma,   // [16]
    float* __restrict__ out)           // [N,N,16]
{
    const int i  = blockIdx.y;
    const int j  = (blockIdx.x << 6) + (threadIdx.x >> 2);  // 64 j per block
    const int c4 = threadIdx.x & 3;

    const float xi = coord[3 * i + 0], yi = coord[3 * i + 1], zi = coord[3 * i + 2];
    const float xj = coord[3 * j + 0], yj = coord[3 * j + 1], zj = coord[3 * j + 2];

    // --- keep decision: EXACT R1/R3 numerics ---
    float sqi = __fadd_rn(__fadd_rn(__fmul_rn(xi, xi), __fmul_rn(yi, yi)),
                          __fmul_rn(zi, zi));
    float sqj = __fadd_rn(__fadd_rn(__fmul_rn(xj, xj), __fmul_rn(yj, yj)),
                          __fmul_rn(zj, zj));
    float dot = __fmul_rn(xi, xj);
    dot = __builtin_fmaf(yi, yj, dot);
    dot = __builtin_fmaf(zi, zj, dot);

    float d2 = __fsub_rn(__fadd_rn(sqi, sqj), __fmul_rn(2.0f, dot));
    d2 = fmaxf(d2, 0.0f);

    bool keep = (i != j) && (d2 > 0.0f) && !(d2 > 2.0f);
    if (keep && d2 > 1.8f) {
        // Rare band (~0.4% of pairs): decide with numpy-matching arithmetic.
        float smax = sigma[15];                                  // 3.0
        float den  = __fmul_rn(__fmul_rn(2.0f, smax), smax);     // 18.0 exact
        float qf   = __fdiv_rn(-d2, den);                        // fp32 rn
        keep = (exp((double)qf) >= 0.9);
    }

    float4 v = make_float4(0.0f, 0.0f, 0.0f, 0.0f);
    if (keep) {
        const float4 s = reinterpret_cast<const float4*>(sigma)[c4];
        // inv = 1/(2*s*s) via native rcp; value tolerance is 0.02, err ~1e-7.
        float i0 = __builtin_amdgcn_rcpf(2.0f * s.x * s.x);
        float i1 = __builtin_amdgcn_rcpf(2.0f * s.y * s.y);
        float i2 = __builtin_amdgcn_rcpf(2.0f * s.z * s.z);
        float i3 = __builtin_amdgcn_rcpf(2.0f * s.w * s.w);
        v.x = __expf(-d2 * i0);
        v.y = __expf(-d2 * i1);
        v.z = __expf(-d2 * i2);
        v.w = __expf(-d2 * i3);
    }

    // float4 slot index: (i*N + j)*4 + c4 == row base + blockIdx.x*256 +
    // threadIdx.x (4 KB contiguous per block). Plain store -> L2 write-combine.
    size_t idx = ((size_t)i * N_PTS << 2) + ((size_t)blockIdx.x << 8) + threadIdx.x;
    reinterpret_cast<float4*>(out)[idx] = v;
}

extern "C" void kernel_launch(void* const* d_in, const int* in_sizes, int n_in,
                              void* d_out, int out_size, void* d_ws, size_t ws_size,
                              hipStream_t stream) {
    const float* coord = (const float*)d_in[0];   // [3072, 3] fp32
    const float* sigma = (const float*)d_in[1];   // [16] fp32
    float* out = (float*)d_out;                   // [1, 3072, 3072, 16] fp32

    dim3 grid(N_PTS / 64, N_PTS);   // (48, 3072)
    dim3 block(256);
    hipLaunchKernelGGL(sparse_edge_kernel, grid, block, 0, stream,
                       coord, sigma, out);
}